// Round 8
// baseline (297.533 us; speedup 1.0000x reference)
//
#include <hip/hip_runtime.h>
#include <hip/hip_bf16.h>

// Problem constants
#define Bsz 4
#define SEQ 1024
#define DIM 512
#define HEADS 8
#define DIM_HEAD 64
#define ROWS (Bsz * SEQ)        // 4096
#define QKV3 (3 * DIM_HEAD)     // 192

typedef _Float16 f16x4 __attribute__((ext_vector_type(4)));
typedef float f32x4 __attribute__((ext_vector_type(4)));

// ---------------------------------------------------------------------------
// LayerNorm: one block per row of x [ROWS, 512]  (unchanged)
// ---------------------------------------------------------------------------
__global__ __launch_bounds__(256) void ln_kernel(
    const float* __restrict__ x, const float* __restrict__ g,
    const float* __restrict__ beta, float* __restrict__ xn)
{
    int r = blockIdx.x;
    int t = threadIdx.x;
    const float* xr = x + (size_t)r * DIM;
    float v0 = xr[t], v1 = xr[t + 256];
    float s = v0 + v1, ss = v0 * v0 + v1 * v1;
    #pragma unroll
    for (int off = 32; off; off >>= 1) {
        s  += __shfl_xor(s, off);
        ss += __shfl_xor(ss, off);
    }
    __shared__ float rs[4], rss[4];
    int wave = t >> 6, lane = t & 63;
    if (lane == 0) { rs[wave] = s; rss[wave] = ss; }
    __syncthreads();
    s  = rs[0] + rs[1] + rs[2] + rs[3];
    ss = rss[0] + rss[1] + rss[2] + rss[3];
    float mu  = s * (1.0f / DIM);
    float var = ss * (1.0f / DIM) - mu * mu;
    float rstd = rsqrtf(var + 1e-5f);
    float* out = xn + (size_t)r * DIM;
    out[t]       = (v0 - mu) * rstd * g[t]       + beta[t];
    out[t + 256] = (v1 - mu) * rstd * g[t + 256] + beta[t + 256];
}

// ---------------------------------------------------------------------------
// fp16-MFMA GEMM (unchanged from round 7)
// ---------------------------------------------------------------------------
template <int TRANS_B>
__global__ __launch_bounds__(256) void gemm16_kernel(
    const float* __restrict__ A, const float* __restrict__ B,
    float* __restrict__ C, const float* __restrict__ bias,
    int K, int lda, int ldb, int ldc,
    long strideA, long strideB, long strideC, float alpha)
{
    int bz = blockIdx.z;
    A += (size_t)bz * strideA;
    B += (size_t)bz * strideB;
    C += (size_t)bz * strideC;

    __shared__ _Float16 As[64][36];
    __shared__ _Float16 Bs[64][36];

    int t = threadIdx.x;
    int block_m = blockIdx.y * 64;
    int block_n = blockIdx.x * 64;
    int wave = t >> 6, lane = t & 63;
    int wm = wave >> 1, wn = wave & 1;
    int lrow = lane & 15, g = lane >> 4;

    int sm = t & 63;
    int kc = t >> 6;

    f32x4 acc[2][2] = {};

    for (int k0 = 0; k0 < K; k0 += 32) {
        {
            const float4* pa = reinterpret_cast<const float4*>(
                A + (size_t)(block_m + sm) * lda + k0 + kc * 8);
            float4 a0 = pa[0], a1 = pa[1];
            f16x4 h0 = { (_Float16)a0.x, (_Float16)a0.y, (_Float16)a0.z, (_Float16)a0.w };
            f16x4 h1 = { (_Float16)a1.x, (_Float16)a1.y, (_Float16)a1.z, (_Float16)a1.w };
            *(f16x4*)&As[sm][kc * 8]     = h0;
            *(f16x4*)&As[sm][kc * 8 + 4] = h1;
        }
        if (TRANS_B) {
            const float4* pb = reinterpret_cast<const float4*>(
                B + (size_t)(block_n + sm) * ldb + k0 + kc * 8);
            float4 b0 = pb[0], b1 = pb[1];
            f16x4 h0 = { (_Float16)b0.x, (_Float16)b0.y, (_Float16)b0.z, (_Float16)b0.w };
            f16x4 h1 = { (_Float16)b1.x, (_Float16)b1.y, (_Float16)b1.z, (_Float16)b1.w };
            *(f16x4*)&Bs[sm][kc * 8]     = h0;
            *(f16x4*)&Bs[sm][kc * 8 + 4] = h1;
        } else {
            const float* pb = B + (size_t)(k0 + kc * 8) * ldb + block_n + sm;
            float b[8];
            #pragma unroll
            for (int i = 0; i < 8; ++i) b[i] = pb[(size_t)i * ldb];
            f16x4 h0 = { (_Float16)b[0], (_Float16)b[1], (_Float16)b[2], (_Float16)b[3] };
            f16x4 h1 = { (_Float16)b[4], (_Float16)b[5], (_Float16)b[6], (_Float16)b[7] };
            *(f16x4*)&Bs[sm][kc * 8]     = h0;
            *(f16x4*)&Bs[sm][kc * 8 + 4] = h1;
        }
        __syncthreads();
        #pragma unroll
        for (int ks = 0; ks < 2; ++ks) {
            f16x4 a0 = *(const f16x4*)&As[32 * wm + lrow][ks * 16 + g * 4];
            f16x4 a1 = *(const f16x4*)&As[32 * wm + 16 + lrow][ks * 16 + g * 4];
            f16x4 b0 = *(const f16x4*)&Bs[32 * wn + lrow][ks * 16 + g * 4];
            f16x4 b1 = *(const f16x4*)&Bs[32 * wn + 16 + lrow][ks * 16 + g * 4];
            acc[0][0] = __builtin_amdgcn_mfma_f32_16x16x16f16(a0, b0, acc[0][0], 0, 0, 0);
            acc[0][1] = __builtin_amdgcn_mfma_f32_16x16x16f16(a0, b1, acc[0][1], 0, 0, 0);
            acc[1][0] = __builtin_amdgcn_mfma_f32_16x16x16f16(a1, b0, acc[1][0], 0, 0, 0);
            acc[1][1] = __builtin_amdgcn_mfma_f32_16x16x16f16(a1, b1, acc[1][1], 0, 0, 0);
        }
        __syncthreads();
    }

    #pragma unroll
    for (int mt = 0; mt < 2; ++mt)
        #pragma unroll
        for (int nt = 0; nt < 2; ++nt) {
            int n = block_n + 32 * wn + 16 * nt + lrow;
            float bv = bias ? bias[n] : 0.0f;
            #pragma unroll
            for (int i = 0; i < 4; ++i) {
                int m = block_m + 32 * wm + 16 * mt + g * 4 + i;
                C[(size_t)m * ldc + n] = acc[mt][nt][i] * alpha + bv;
            }
        }
}

// ---------------------------------------------------------------------------
// FUSED LML solve + PV. One 4-wave block per row.
// Solve: wave w solves nu for N = 2w+1, 2w+2 (byte-identical 12-bisection +
// 5-guarded-Newton sequence from rounds 6/7; per-nu arithmetic, reductions,
// and bracket decisions bitwise unchanged). Then each wave writes p for its
// 2 nus directly from register-resident e^x into p_lds[8][1024] (32 KB),
// one barrier, and the round-6 PV loop runs (wave = j-quarter, all 8 heads;
// 8 broadcast float4 reads per 4 j = same 2 b128/j as before). ow overlays
// dead p_lds space. Eliminates: dots re-read, 4.2M expf recomputes, nu
// round-trip, one kernel launch.
// ---------------------------------------------------------------------------
__global__ __launch_bounds__(256) void solve_pv_kernel(
    const float* __restrict__ dots, const float* __restrict__ qkv,
    float* __restrict__ y)
{
    int r = blockIdx.x;
    int b = r >> 10;
    int t = threadIdx.x;
    int wave = t >> 6, lane = t & 63;
    int nbase = wave * 2;            // this wave solves N = nbase+1, nbase+2

    __shared__ float p_lds[8][1024];  // 32 KB; first 8 KB reused as ow later

    const float* x = dots + (size_t)r * SEQ;

    float e[16];
    #pragma unroll
    for (int s = 0; s < 4; ++s) {
        float4 v = *(const float4*)(x + lane * 4 + 256 * s);
        e[4 * s + 0] = v.x; e[4 * s + 1] = v.y;
        e[4 * s + 2] = v.z; e[4 * s + 3] = v.w;
    }
    float mx = e[0], mn = e[0];
    #pragma unroll
    for (int s = 1; s < 16; ++s) { mx = fmaxf(mx, e[s]); mn = fminf(mn, e[s]); }
    #pragma unroll
    for (int off = 32; off; off >>= 1) {
        mx = fmaxf(mx, __shfl_xor(mx, off));
        mn = fminf(mn, __shfl_xor(mn, off));
    }
    #pragma unroll
    for (int s = 0; s < 16; ++s) e[s] = __expf(e[s]);

    float lo[2], hi[2], Nf[2];
    #pragma unroll
    for (int k = 0; k < 2; ++k) {
        int N = nbase + k + 1;
        Nf[k] = (float)N;
        float lgt = __logf((float)N / (float)(SEQ - N));
        lo[k] = lgt - mx;
        hi[k] = lgt - mn;
    }

    // ---- 12 bisection iterations ----
    for (int it = 0; it < 12; ++it) {
        float S[2];
        #pragma unroll
        for (int k = 0; k < 2; ++k) {
            float mid = 0.5f * (lo[k] + hi[k]);
            float tn = __expf(mid);
            float sn = 0.0f;
            #pragma unroll
            for (int s = 0; s < 8; ++s) {
                float u1 = e[2 * s] * tn, u2 = e[2 * s + 1] * tn;
                float a1 = 1.0f + u1, a2 = 1.0f + u2;
                float rr = __builtin_amdgcn_rcpf(a1 * a2);
                float num = fmaf(u1, a2, u2 * a1);
                sn = fmaf(num, rr, sn);
            }
            S[k] = sn;
        }
        #pragma unroll
        for (int k = 0; k < 2; ++k) {
            #pragma unroll
            for (int off = 32; off; off >>= 1) S[k] += __shfl_xor(S[k], off);
            float mid = 0.5f * (lo[k] + hi[k]);
            if (S[k] < Nf[k]) lo[k] = mid; else hi[k] = mid;
        }
    }

    float nu[2];
    #pragma unroll
    for (int k = 0; k < 2; ++k) nu[k] = 0.5f * (lo[k] + hi[k]);

    // ---- 5 guarded Newton iterations ----
    for (int it = 0; it < 5; ++it) {
        float S[2], Sp[2];
        #pragma unroll
        for (int k = 0; k < 2; ++k) {
            float tn = __expf(nu[k]);
            float sn = 0.0f, spn = 0.0f;
            #pragma unroll
            for (int s = 0; s < 8; ++s) {
                float u1 = e[2 * s] * tn, u2 = e[2 * s + 1] * tn;
                float a1 = 1.0f + u1, a2 = 1.0f + u2;
                float rr = __builtin_amdgcn_rcpf(a1 * a2);
                float inv1 = rr * a2, inv2 = rr * a1;
                float p1 = u1 * inv1, p2 = u2 * inv2;
                sn += p1 + p2;
                spn = fmaf(p1, inv1, spn);
                spn = fmaf(p2, inv2, spn);
            }
            S[k] = sn; Sp[k] = spn;
        }
        #pragma unroll
        for (int k = 0; k < 2; ++k) {
            #pragma unroll
            for (int off = 32; off; off >>= 1) {
                S[k]  += __shfl_xor(S[k], off);
                Sp[k] += __shfl_xor(Sp[k], off);
            }
            if (S[k] < Nf[k]) lo[k] = nu[k]; else hi[k] = nu[k];
            float step = (Nf[k] - S[k]) * __builtin_amdgcn_rcpf(Sp[k]);
            float cand = nu[k] + step;
            if (!(cand > lo[k] && cand < hi[k])) cand = 0.5f * (lo[k] + hi[k]);
            nu[k] = cand;
        }
    }

    // ---- write p for this wave's 2 nus from register e[] ----
    #pragma unroll
    for (int k = 0; k < 2; ++k) {
        float tn = __expf(nu[k]);
        #pragma unroll
        for (int s = 0; s < 4; ++s) {
            float u0 = e[4 * s + 0] * tn, u1 = e[4 * s + 1] * tn;
            float u2 = e[4 * s + 2] * tn, u3 = e[4 * s + 3] * tn;
            float4 pp;
            pp.x = u0 * __builtin_amdgcn_rcpf(1.0f + u0);
            pp.y = u1 * __builtin_amdgcn_rcpf(1.0f + u1);
            pp.z = u2 * __builtin_amdgcn_rcpf(1.0f + u2);
            pp.w = u3 * __builtin_amdgcn_rcpf(1.0f + u3);
            *(float4*)&p_lds[nbase + k][lane * 4 + 256 * s] = pp;
        }
    }
    __syncthreads();

    // ---- PV: wave w covers j in [256w, 256w+256), lane = d, all 8 heads ----
    int jbase = wave * 256;
    const float* vbase = qkv + ((size_t)b * SEQ + jbase) * QKV3 + 2 * DIM_HEAD + lane;
    float acc[8] = {};
    for (int j4 = 0; j4 < 256; j4 += 4) {
        float4 p0 = *(const float4*)&p_lds[0][jbase + j4];
        float4 p1 = *(const float4*)&p_lds[1][jbase + j4];
        float4 p2 = *(const float4*)&p_lds[2][jbase + j4];
        float4 p3 = *(const float4*)&p_lds[3][jbase + j4];
        float4 p4 = *(const float4*)&p_lds[4][jbase + j4];
        float4 p5 = *(const float4*)&p_lds[5][jbase + j4];
        float4 p6 = *(const float4*)&p_lds[6][jbase + j4];
        float4 p7 = *(const float4*)&p_lds[7][jbase + j4];
        float v0 = vbase[(size_t)(j4 + 0) * QKV3];
        float v1 = vbase[(size_t)(j4 + 1) * QKV3];
        float v2 = vbase[(size_t)(j4 + 2) * QKV3];
        float v3 = vbase[(size_t)(j4 + 3) * QKV3];
        acc[0] = fmaf(p0.x, v0, acc[0]); acc[1] = fmaf(p1.x, v0, acc[1]);
        acc[2] = fmaf(p2.x, v0, acc[2]); acc[3] = fmaf(p3.x, v0, acc[3]);
        acc[4] = fmaf(p4.x, v0, acc[4]); acc[5] = fmaf(p5.x, v0, acc[5]);
        acc[6] = fmaf(p6.x, v0, acc[6]); acc[7] = fmaf(p7.x, v0, acc[7]);
        acc[0] = fmaf(p0.y, v1, acc[0]); acc[1] = fmaf(p1.y, v1, acc[1]);
        acc[2] = fmaf(p2.y, v1, acc[2]); acc[3] = fmaf(p3.y, v1, acc[3]);
        acc[4] = fmaf(p4.y, v1, acc[4]); acc[5] = fmaf(p5.y, v1, acc[5]);
        acc[6] = fmaf(p6.y, v1, acc[6]); acc[7] = fmaf(p7.y, v1, acc[7]);
        acc[0] = fmaf(p0.z, v2, acc[0]); acc[1] = fmaf(p1.z, v2, acc[1]);
        acc[2] = fmaf(p2.z, v2, acc[2]); acc[3] = fmaf(p3.z, v2, acc[3]);
        acc[4] = fmaf(p4.z, v2, acc[4]); acc[5] = fmaf(p5.z, v2, acc[5]);
        acc[6] = fmaf(p6.z, v2, acc[6]); acc[7] = fmaf(p7.z, v2, acc[7]);
        acc[0] = fmaf(p0.w, v3, acc[0]); acc[1] = fmaf(p1.w, v3, acc[1]);
        acc[2] = fmaf(p2.w, v3, acc[2]); acc[3] = fmaf(p3.w, v3, acc[3]);
        acc[4] = fmaf(p4.w, v3, acc[4]); acc[5] = fmaf(p5.w, v3, acc[5]);
        acc[6] = fmaf(p6.w, v3, acc[6]); acc[7] = fmaf(p7.w, v3, acc[7]);
    }
    __syncthreads();   // all p reads done; safe to overlay ow on p_lds

    float (*ow)[8][64] = (float (*)[8][64])&p_lds[0][0];   // 8 KB overlay
    #pragma unroll
    for (int n = 0; n < 8; ++n) ow[wave][n][lane] = acc[n];
    __syncthreads();

    // reduce across waves + head differences -> y[r][h*64+d]
    float* yr = y + (size_t)r * (HEADS * DIM_HEAD);
    #pragma unroll
    for (int s = 0; s < 2; ++s) {
        int c = t + 256 * s;
        int h = c >> 6, dd = c & 63;
        float oh = ow[0][h][dd] + ow[1][h][dd] + ow[2][h][dd] + ow[3][h][dd];
        float op = 0.0f;
        if (h) op = ow[0][h - 1][dd] + ow[1][h - 1][dd] + ow[2][h - 1][dd] + ow[3][h - 1][dd];
        yr[c] = oh - op;
    }
}

// ---------------------------------------------------------------------------
extern "C" void kernel_launch(void* const* d_in, const int* in_sizes, int n_in,
                              void* d_out, int out_size, void* d_ws, size_t ws_size,
                              hipStream_t stream)
{
    const float* x       = (const float*)d_in[0];
    const float* ln_g    = (const float*)d_in[1];
    const float* ln_b    = (const float*)d_in[2];
    const float* w_qkv   = (const float*)d_in[3];
    const float* w_out   = (const float*)d_in[4];
    const float* b_out   = (const float*)d_in[5];
    float* out = (float*)d_out;

    // ws: xn[ROWS*DIM] | qkv[ROWS*192] | dots[4M]   (~28.5 MB)
    float* xn   = (float*)d_ws;
    float* qkv  = xn + (size_t)ROWS * DIM;
    float* dots = qkv + (size_t)ROWS * QKV3;
    float* y    = xn;  // reuse (dead after qkv GEMM; rewritten by solve_pv)

    // 1) LayerNorm
    ln_kernel<<<ROWS, 256, 0, stream>>>(x, ln_g, ln_b, xn);

    // 2) qkv = xn @ w_qkv   [4096,512]x[512,192]
    gemm16_kernel<0><<<dim3(QKV3 / 64, ROWS / 64, 1), 256, 0, stream>>>(
        xn, w_qkv, qkv, nullptr,
        DIM, DIM, QKV3, QKV3, 0, 0, 0, 1.0f);

    // 3) dots[b] = 0.125 * q[b] @ k[b]^T   batched [1024,64]x[64,1024]
    gemm16_kernel<1><<<dim3(SEQ / 64, SEQ / 64, Bsz), 256, 0, stream>>>(
        qkv, qkv + DIM_HEAD, dots, nullptr,
        DIM_HEAD, QKV3, QKV3, SEQ,
        (long)SEQ * QKV3, (long)SEQ * QKV3, (long)SEQ * SEQ, 0.125f);

    // 4) fused LML solve + PV + head differences -> y [4096, 512]
    solve_pv_kernel<<<ROWS, 256, 0, stream>>>(dots, qkv, y);

    // 5) out = y @ w_out + b_out   [4096,512]x[512,512]
    gemm16_kernel<0><<<dim3(DIM / 64, ROWS / 64, 1), 256, 0, stream>>>(
        y, w_out, out, b_out,
        DIM, DIM, DIM, DIM, 0, 0, 0, 1.0f);
}

// Round 9
// 241.480 us; speedup vs baseline: 1.2321x; 1.2321x over previous
//
#include <hip/hip_runtime.h>
#include <hip/hip_bf16.h>

// Problem constants
#define Bsz 4
#define SEQ 1024
#define DIM 512
#define HEADS 8
#define DIM_HEAD 64
#define ROWS (Bsz * SEQ)        // 4096
#define QKV3 (3 * DIM_HEAD)     // 192

typedef _Float16 f16x4 __attribute__((ext_vector_type(4)));
typedef float f32x4 __attribute__((ext_vector_type(4)));

// ---------------------------------------------------------------------------
// LayerNorm: one block per row of x [ROWS, 512]  (unchanged)
// ---------------------------------------------------------------------------
__global__ __launch_bounds__(256) void ln_kernel(
    const float* __restrict__ x, const float* __restrict__ g,
    const float* __restrict__ beta, float* __restrict__ xn)
{
    int r = blockIdx.x;
    int t = threadIdx.x;
    const float* xr = x + (size_t)r * DIM;
    float v0 = xr[t], v1 = xr[t + 256];
    float s = v0 + v1, ss = v0 * v0 + v1 * v1;
    #pragma unroll
    for (int off = 32; off; off >>= 1) {
        s  += __shfl_xor(s, off);
        ss += __shfl_xor(ss, off);
    }
    __shared__ float rs[4], rss[4];
    int wave = t >> 6, lane = t & 63;
    if (lane == 0) { rs[wave] = s; rss[wave] = ss; }
    __syncthreads();
    s  = rs[0] + rs[1] + rs[2] + rs[3];
    ss = rss[0] + rss[1] + rss[2] + rss[3];
    float mu  = s * (1.0f / DIM);
    float var = ss * (1.0f / DIM) - mu * mu;
    float rstd = rsqrtf(var + 1e-5f);
    float* out = xn + (size_t)r * DIM;
    out[t]       = (v0 - mu) * rstd * g[t]       + beta[t];
    out[t + 256] = (v1 - mu) * rstd * g[t + 256] + beta[t + 256];
}

// ---------------------------------------------------------------------------
// fp16-MFMA GEMM (unchanged from round 7)
// ---------------------------------------------------------------------------
template <int TRANS_B>
__global__ __launch_bounds__(256) void gemm16_kernel(
    const float* __restrict__ A, const float* __restrict__ B,
    float* __restrict__ C, const float* __restrict__ bias,
    int K, int lda, int ldb, int ldc,
    long strideA, long strideB, long strideC, float alpha)
{
    int bz = blockIdx.z;
    A += (size_t)bz * strideA;
    B += (size_t)bz * strideB;
    C += (size_t)bz * strideC;

    __shared__ _Float16 As[64][36];
    __shared__ _Float16 Bs[64][36];

    int t = threadIdx.x;
    int block_m = blockIdx.y * 64;
    int block_n = blockIdx.x * 64;
    int wave = t >> 6, lane = t & 63;
    int wm = wave >> 1, wn = wave & 1;
    int lrow = lane & 15, g = lane >> 4;

    int sm = t & 63;
    int kc = t >> 6;

    f32x4 acc[2][2] = {};

    for (int k0 = 0; k0 < K; k0 += 32) {
        {
            const float4* pa = reinterpret_cast<const float4*>(
                A + (size_t)(block_m + sm) * lda + k0 + kc * 8);
            float4 a0 = pa[0], a1 = pa[1];
            f16x4 h0 = { (_Float16)a0.x, (_Float16)a0.y, (_Float16)a0.z, (_Float16)a0.w };
            f16x4 h1 = { (_Float16)a1.x, (_Float16)a1.y, (_Float16)a1.z, (_Float16)a1.w };
            *(f16x4*)&As[sm][kc * 8]     = h0;
            *(f16x4*)&As[sm][kc * 8 + 4] = h1;
        }
        if (TRANS_B) {
            const float4* pb = reinterpret_cast<const float4*>(
                B + (size_t)(block_n + sm) * ldb + k0 + kc * 8);
            float4 b0 = pb[0], b1 = pb[1];
            f16x4 h0 = { (_Float16)b0.x, (_Float16)b0.y, (_Float16)b0.z, (_Float16)b0.w };
            f16x4 h1 = { (_Float16)b1.x, (_Float16)b1.y, (_Float16)b1.z, (_Float16)b1.w };
            *(f16x4*)&Bs[sm][kc * 8]     = h0;
            *(f16x4*)&Bs[sm][kc * 8 + 4] = h1;
        } else {
            const float* pb = B + (size_t)(k0 + kc * 8) * ldb + block_n + sm;
            float b[8];
            #pragma unroll
            for (int i = 0; i < 8; ++i) b[i] = pb[(size_t)i * ldb];
            f16x4 h0 = { (_Float16)b[0], (_Float16)b[1], (_Float16)b[2], (_Float16)b[3] };
            f16x4 h1 = { (_Float16)b[4], (_Float16)b[5], (_Float16)b[6], (_Float16)b[7] };
            *(f16x4*)&Bs[sm][kc * 8]     = h0;
            *(f16x4*)&Bs[sm][kc * 8 + 4] = h1;
        }
        __syncthreads();
        #pragma unroll
        for (int ks = 0; ks < 2; ++ks) {
            f16x4 a0 = *(const f16x4*)&As[32 * wm + lrow][ks * 16 + g * 4];
            f16x4 a1 = *(const f16x4*)&As[32 * wm + 16 + lrow][ks * 16 + g * 4];
            f16x4 b0 = *(const f16x4*)&Bs[32 * wn + lrow][ks * 16 + g * 4];
            f16x4 b1 = *(const f16x4*)&Bs[32 * wn + 16 + lrow][ks * 16 + g * 4];
            acc[0][0] = __builtin_amdgcn_mfma_f32_16x16x16f16(a0, b0, acc[0][0], 0, 0, 0);
            acc[0][1] = __builtin_amdgcn_mfma_f32_16x16x16f16(a0, b1, acc[0][1], 0, 0, 0);
            acc[1][0] = __builtin_amdgcn_mfma_f32_16x16x16f16(a1, b0, acc[1][0], 0, 0, 0);
            acc[1][1] = __builtin_amdgcn_mfma_f32_16x16x16f16(a1, b1, acc[1][1], 0, 0, 0);
        }
        __syncthreads();
    }

    #pragma unroll
    for (int mt = 0; mt < 2; ++mt)
        #pragma unroll
        for (int nt = 0; nt < 2; ++nt) {
            int n = block_n + 32 * wn + 16 * nt + lrow;
            float bv = bias ? bias[n] : 0.0f;
            #pragma unroll
            for (int i = 0; i < 4; ++i) {
                int m = block_m + 32 * wm + 16 * mt + g * 4 + i;
                C[(size_t)m * ldc + n] = acc[mt][nt][i] * alpha + bv;
            }
        }
}

// ---------------------------------------------------------------------------
// FUSED LML solve + PV. One 4-wave block per row; wave w solves nu for
// N = 2w+1, 2w+2.
//
// Solver schedule (round-9): quartic-SERIES init + 4 bracket-guarded full
// Newton evals. Since sum sigmoid = N <= 8 over 1024 terms, u = e^{x+nu} is
// O(N/1024 * e^{mx-mn}) ~ 0.01, so S(t) = E1 t - E2 t^2 + E3 t^3 - E4 t^4
// (t = e^nu, E_k = sum e^{k x}) has relative truncation error ~u^4 ~ 1e-8.
// Scalar Newton on the quartic costs no per-element work.
//
// GUARD FIX (root cause of rounds 2/4 accuracy failures): after setting
// lo=nu (or hi=nu), a converged Newton step gives cand == lo; the old
// STRICT test (cand > lo && cand < hi) rejected it and teleported to
// mid-bracket -- sabotaging Newton exactly at convergence. Inclusive
// bounds (>=, <=) let converged iterates stay. Worst case (series
// rejected -> mid of ~1.3-wide bracket), 4 guarded Newtons contract
// 0.65 -> 0.21 -> 0.022 -> 2.4e-4 -> noise.
// ---------------------------------------------------------------------------
__global__ __launch_bounds__(256) void solve_pv_kernel(
    const float* __restrict__ dots, const float* __restrict__ qkv,
    float* __restrict__ y)
{
    int r = blockIdx.x;
    int b = r >> 10;
    int t = threadIdx.x;
    int wave = t >> 6, lane = t & 63;
    int nbase = wave * 2;            // this wave solves N = nbase+1, nbase+2

    __shared__ float p_lds[8][1024];  // 32 KB; first 8 KB reused as ow later

    const float* x = dots + (size_t)r * SEQ;

    float e[16];
    #pragma unroll
    for (int s = 0; s < 4; ++s) {
        float4 v = *(const float4*)(x + lane * 4 + 256 * s);
        e[4 * s + 0] = v.x; e[4 * s + 1] = v.y;
        e[4 * s + 2] = v.z; e[4 * s + 3] = v.w;
    }
    float mx = e[0], mn = e[0];
    #pragma unroll
    for (int s = 1; s < 16; ++s) { mx = fmaxf(mx, e[s]); mn = fminf(mn, e[s]); }
    #pragma unroll
    for (int off = 32; off; off >>= 1) {
        mx = fmaxf(mx, __shfl_xor(mx, off));
        mn = fminf(mn, __shfl_xor(mn, off));
    }
    #pragma unroll
    for (int s = 0; s < 16; ++s) e[s] = __expf(e[s]);

    // E1..E4 = sums of e^x, e^2x, e^3x, e^4x (for the series init)
    float E1 = 0, E2 = 0, E3 = 0, E4 = 0;
    #pragma unroll
    for (int s = 0; s < 16; ++s) {
        float u = e[s], u2 = u * u;
        E1 += u; E2 += u2; E3 += u2 * u; E4 += u2 * u2;
    }
    #pragma unroll
    for (int off = 32; off; off >>= 1) {
        E1 += __shfl_xor(E1, off); E2 += __shfl_xor(E2, off);
        E3 += __shfl_xor(E3, off); E4 += __shfl_xor(E4, off);
    }

    float lo[2], hi[2], Nf[2], nu[2];
    #pragma unroll
    for (int k = 0; k < 2; ++k) {
        int N = nbase + k + 1;
        Nf[k] = (float)N;
        float lgt = __logf((float)N / (float)(SEQ - N));
        lo[k] = lgt - mx;             // provable bracket
        hi[k] = lgt - mn;
        // scalar Newton on the quartic series in t = e^nu
        float t0 = Nf[k] * __builtin_amdgcn_rcpf(E1);
        float tt = t0;
        #pragma unroll
        for (int it = 0; it < 4; ++it) {
            float gg = tt * (E1 + tt * (-E2 + tt * (E3 - tt * E4))) - Nf[k];
            float gp = E1 + tt * (-2.0f * E2 + tt * (3.0f * E3 - 4.0f * E4 * tt));
            float tn = tt - gg * __builtin_amdgcn_rcpf(gp);
            tt = (tn > 0.0f && tn < 1.0f) ? tn : t0;
        }
        float v = __logf(tt);
        nu[k] = (v > lo[k] && v < hi[k]) ? v : 0.5f * (lo[k] + hi[k]);
    }

    // ---- 4 bracket-guarded full Newton evals (inclusive-bound guard) ----
    for (int it = 0; it < 4; ++it) {
        float S[2], Sp[2];
        #pragma unroll
        for (int k = 0; k < 2; ++k) {
            float tn = __expf(nu[k]);
            float sn = 0.0f, spn = 0.0f;
            #pragma unroll
            for (int s = 0; s < 8; ++s) {
                float u1 = e[2 * s] * tn, u2 = e[2 * s + 1] * tn;
                float a1 = 1.0f + u1, a2 = 1.0f + u2;
                float rr = __builtin_amdgcn_rcpf(a1 * a2);
                float inv1 = rr * a2, inv2 = rr * a1;     // = 1/a1, 1/a2
                float p1 = u1 * inv1, p2 = u2 * inv2;
                sn += p1 + p2;
                spn = fmaf(p1, inv1, spn);                // p(1-p) = p*inv
                spn = fmaf(p2, inv2, spn);
            }
            S[k] = sn; Sp[k] = spn;
        }
        #pragma unroll
        for (int k = 0; k < 2; ++k) {
            #pragma unroll
            for (int off = 32; off; off >>= 1) {
                S[k]  += __shfl_xor(S[k], off);
                Sp[k] += __shfl_xor(Sp[k], off);
            }
            if (S[k] < Nf[k]) lo[k] = nu[k]; else hi[k] = nu[k];
            float step = (Nf[k] - S[k]) * __builtin_amdgcn_rcpf(Sp[k]);
            float cand = nu[k] + step;
            if (!(cand >= lo[k] && cand <= hi[k])) cand = 0.5f * (lo[k] + hi[k]);
            nu[k] = cand;
        }
    }

    // ---- write p for this wave's 2 nus from register e[] ----
    #pragma unroll
    for (int k = 0; k < 2; ++k) {
        float tn = __expf(nu[k]);
        #pragma unroll
        for (int s = 0; s < 4; ++s) {
            float u0 = e[4 * s + 0] * tn, u1 = e[4 * s + 1] * tn;
            float u2 = e[4 * s + 2] * tn, u3 = e[4 * s + 3] * tn;
            float4 pp;
            pp.x = u0 * __builtin_amdgcn_rcpf(1.0f + u0);
            pp.y = u1 * __builtin_amdgcn_rcpf(1.0f + u1);
            pp.z = u2 * __builtin_amdgcn_rcpf(1.0f + u2);
            pp.w = u3 * __builtin_amdgcn_rcpf(1.0f + u3);
            *(float4*)&p_lds[nbase + k][lane * 4 + 256 * s] = pp;
        }
    }
    __syncthreads();

    // ---- PV: wave w covers j in [256w, 256w+256), lane = d, all 8 heads ----
    int jbase = wave * 256;
    const float* vbase = qkv + ((size_t)b * SEQ + jbase) * QKV3 + 2 * DIM_HEAD + lane;
    float acc[8] = {};
    for (int j4 = 0; j4 < 256; j4 += 4) {
        float4 p0 = *(const float4*)&p_lds[0][jbase + j4];
        float4 p1 = *(const float4*)&p_lds[1][jbase + j4];
        float4 p2 = *(const float4*)&p_lds[2][jbase + j4];
        float4 p3 = *(const float4*)&p_lds[3][jbase + j4];
        float4 p4 = *(const float4*)&p_lds[4][jbase + j4];
        float4 p5 = *(const float4*)&p_lds[5][jbase + j4];
        float4 p6 = *(const float4*)&p_lds[6][jbase + j4];
        float4 p7 = *(const float4*)&p_lds[7][jbase + j4];
        float v0 = vbase[(size_t)(j4 + 0) * QKV3];
        float v1 = vbase[(size_t)(j4 + 1) * QKV3];
        float v2 = vbase[(size_t)(j4 + 2) * QKV3];
        float v3 = vbase[(size_t)(j4 + 3) * QKV3];
        acc[0] = fmaf(p0.x, v0, acc[0]); acc[1] = fmaf(p1.x, v0, acc[1]);
        acc[2] = fmaf(p2.x, v0, acc[2]); acc[3] = fmaf(p3.x, v0, acc[3]);
        acc[4] = fmaf(p4.x, v0, acc[4]); acc[5] = fmaf(p5.x, v0, acc[5]);
        acc[6] = fmaf(p6.x, v0, acc[6]); acc[7] = fmaf(p7.x, v0, acc[7]);
        acc[0] = fmaf(p0.y, v1, acc[0]); acc[1] = fmaf(p1.y, v1, acc[1]);
        acc[2] = fmaf(p2.y, v1, acc[2]); acc[3] = fmaf(p3.y, v1, acc[3]);
        acc[4] = fmaf(p4.y, v1, acc[4]); acc[5] = fmaf(p5.y, v1, acc[5]);
        acc[6] = fmaf(p6.y, v1, acc[6]); acc[7] = fmaf(p7.y, v1, acc[7]);
        acc[0] = fmaf(p0.z, v2, acc[0]); acc[1] = fmaf(p1.z, v2, acc[1]);
        acc[2] = fmaf(p2.z, v2, acc[2]); acc[3] = fmaf(p3.z, v2, acc[3]);
        acc[4] = fmaf(p4.z, v2, acc[4]); acc[5] = fmaf(p5.z, v2, acc[5]);
        acc[6] = fmaf(p6.z, v2, acc[6]); acc[7] = fmaf(p7.z, v2, acc[7]);
        acc[0] = fmaf(p0.w, v3, acc[0]); acc[1] = fmaf(p1.w, v3, acc[1]);
        acc[2] = fmaf(p2.w, v3, acc[2]); acc[3] = fmaf(p3.w, v3, acc[3]);
        acc[4] = fmaf(p4.w, v3, acc[4]); acc[5] = fmaf(p5.w, v3, acc[5]);
        acc[6] = fmaf(p6.w, v3, acc[6]); acc[7] = fmaf(p7.w, v3, acc[7]);
    }
    __syncthreads();   // all p reads done; safe to overlay ow on p_lds

    float (*ow)[8][64] = (float (*)[8][64])&p_lds[0][0];   // 8 KB overlay
    #pragma unroll
    for (int n = 0; n < 8; ++n) ow[wave][n][lane] = acc[n];
    __syncthreads();

    // reduce across waves + head differences -> y[r][h*64+d]
    float* yr = y + (size_t)r * (HEADS * DIM_HEAD);
    #pragma unroll
    for (int s = 0; s < 2; ++s) {
        int c = t + 256 * s;
        int h = c >> 6, dd = c & 63;
        float oh = ow[0][h][dd] + ow[1][h][dd] + ow[2][h][dd] + ow[3][h][dd];
        float op = 0.0f;
        if (h) op = ow[0][h - 1][dd] + ow[1][h - 1][dd] + ow[2][h - 1][dd] + ow[3][h - 1][dd];
        yr[c] = oh - op;
    }
}

// ---------------------------------------------------------------------------
extern "C" void kernel_launch(void* const* d_in, const int* in_sizes, int n_in,
                              void* d_out, int out_size, void* d_ws, size_t ws_size,
                              hipStream_t stream)
{
    const float* x       = (const float*)d_in[0];
    const float* ln_g    = (const float*)d_in[1];
    const float* ln_b    = (const float*)d_in[2];
    const float* w_qkv   = (const float*)d_in[3];
    const float* w_out   = (const float*)d_in[4];
    const float* b_out   = (const float*)d_in[5];
    float* out = (float*)d_out;

    // ws: xn[ROWS*DIM] | qkv[ROWS*192] | dots[4M]   (~28.5 MB)
    float* xn   = (float*)d_ws;
    float* qkv  = xn + (size_t)ROWS * DIM;
    float* dots = qkv + (size_t)ROWS * QKV3;
    float* y    = xn;  // reuse (dead after qkv GEMM; rewritten by solve_pv)

    // 1) LayerNorm
    ln_kernel<<<ROWS, 256, 0, stream>>>(x, ln_g, ln_b, xn);

    // 2) qkv = xn @ w_qkv   [4096,512]x[512,192]
    gemm16_kernel<0><<<dim3(QKV3 / 64, ROWS / 64, 1), 256, 0, stream>>>(
        xn, w_qkv, qkv, nullptr,
        DIM, DIM, QKV3, QKV3, 0, 0, 0, 1.0f);

    // 3) dots[b] = 0.125 * q[b] @ k[b]^T   batched [1024,64]x[64,1024]
    gemm16_kernel<1><<<dim3(SEQ / 64, SEQ / 64, Bsz), 256, 0, stream>>>(
        qkv, qkv + DIM_HEAD, dots, nullptr,
        DIM_HEAD, QKV3, QKV3, SEQ,
        (long)SEQ * QKV3, (long)SEQ * QKV3, (long)SEQ * SEQ, 0.125f);

    // 4) fused LML solve + PV + head differences -> y [4096, 512]
    solve_pv_kernel<<<ROWS, 256, 0, stream>>>(dots, qkv, y);

    // 5) out = y @ w_out + b_out   [4096,512]x[512,512]
    gemm16_kernel<0><<<dim3(DIM / 64, ROWS / 64, 1), 256, 0, stream>>>(
        y, w_out, out, b_out,
        DIM, DIM, DIM, DIM, 0, 0, 0, 1.0f);
}

// Round 10
// 220.297 us; speedup vs baseline: 1.3506x; 1.0962x over previous
//
#include <hip/hip_runtime.h>
#include <hip/hip_bf16.h>

// Problem constants
#define Bsz 4
#define SEQ 1024
#define DIM 512
#define HEADS 8
#define DIM_HEAD 64
#define ROWS (Bsz * SEQ)        // 4096
#define QKV3 (3 * DIM_HEAD)     // 192

typedef _Float16 f16x4 __attribute__((ext_vector_type(4)));
typedef float f32x4 __attribute__((ext_vector_type(4)));

// ---------------------------------------------------------------------------
// LayerNorm: one block per row of x [ROWS, 512]  (unchanged)
// ---------------------------------------------------------------------------
__global__ __launch_bounds__(256) void ln_kernel(
    const float* __restrict__ x, const float* __restrict__ g,
    const float* __restrict__ beta, float* __restrict__ xn)
{
    int r = blockIdx.x;
    int t = threadIdx.x;
    const float* xr = x + (size_t)r * DIM;
    float v0 = xr[t], v1 = xr[t + 256];
    float s = v0 + v1, ss = v0 * v0 + v1 * v1;
    #pragma unroll
    for (int off = 32; off; off >>= 1) {
        s  += __shfl_xor(s, off);
        ss += __shfl_xor(ss, off);
    }
    __shared__ float rs[4], rss[4];
    int wave = t >> 6, lane = t & 63;
    if (lane == 0) { rs[wave] = s; rss[wave] = ss; }
    __syncthreads();
    s  = rs[0] + rs[1] + rs[2] + rs[3];
    ss = rss[0] + rss[1] + rss[2] + rss[3];
    float mu  = s * (1.0f / DIM);
    float var = ss * (1.0f / DIM) - mu * mu;
    float rstd = rsqrtf(var + 1e-5f);
    float* out = xn + (size_t)r * DIM;
    out[t]       = (v0 - mu) * rstd * g[t]       + beta[t];
    out[t + 256] = (v1 - mu) * rstd * g[t + 256] + beta[t + 256];
}

// ---------------------------------------------------------------------------
// fp16-MFMA GEMM (unchanged from round 7)
// ---------------------------------------------------------------------------
template <int TRANS_B>
__global__ __launch_bounds__(256) void gemm16_kernel(
    const float* __restrict__ A, const float* __restrict__ B,
    float* __restrict__ C, const float* __restrict__ bias,
    int K, int lda, int ldb, int ldc,
    long strideA, long strideB, long strideC, float alpha)
{
    int bz = blockIdx.z;
    A += (size_t)bz * strideA;
    B += (size_t)bz * strideB;
    C += (size_t)bz * strideC;

    __shared__ _Float16 As[64][36];
    __shared__ _Float16 Bs[64][36];

    int t = threadIdx.x;
    int block_m = blockIdx.y * 64;
    int block_n = blockIdx.x * 64;
    int wave = t >> 6, lane = t & 63;
    int wm = wave >> 1, wn = wave & 1;
    int lrow = lane & 15, g = lane >> 4;

    int sm = t & 63;
    int kc = t >> 6;

    f32x4 acc[2][2] = {};

    for (int k0 = 0; k0 < K; k0 += 32) {
        {
            const float4* pa = reinterpret_cast<const float4*>(
                A + (size_t)(block_m + sm) * lda + k0 + kc * 8);
            float4 a0 = pa[0], a1 = pa[1];
            f16x4 h0 = { (_Float16)a0.x, (_Float16)a0.y, (_Float16)a0.z, (_Float16)a0.w };
            f16x4 h1 = { (_Float16)a1.x, (_Float16)a1.y, (_Float16)a1.z, (_Float16)a1.w };
            *(f16x4*)&As[sm][kc * 8]     = h0;
            *(f16x4*)&As[sm][kc * 8 + 4] = h1;
        }
        if (TRANS_B) {
            const float4* pb = reinterpret_cast<const float4*>(
                B + (size_t)(block_n + sm) * ldb + k0 + kc * 8);
            float4 b0 = pb[0], b1 = pb[1];
            f16x4 h0 = { (_Float16)b0.x, (_Float16)b0.y, (_Float16)b0.z, (_Float16)b0.w };
            f16x4 h1 = { (_Float16)b1.x, (_Float16)b1.y, (_Float16)b1.z, (_Float16)b1.w };
            *(f16x4*)&Bs[sm][kc * 8]     = h0;
            *(f16x4*)&Bs[sm][kc * 8 + 4] = h1;
        } else {
            const float* pb = B + (size_t)(k0 + kc * 8) * ldb + block_n + sm;
            float b[8];
            #pragma unroll
            for (int i = 0; i < 8; ++i) b[i] = pb[(size_t)i * ldb];
            f16x4 h0 = { (_Float16)b[0], (_Float16)b[1], (_Float16)b[2], (_Float16)b[3] };
            f16x4 h1 = { (_Float16)b[4], (_Float16)b[5], (_Float16)b[6], (_Float16)b[7] };
            *(f16x4*)&Bs[sm][kc * 8]     = h0;
            *(f16x4*)&Bs[sm][kc * 8 + 4] = h1;
        }
        __syncthreads();
        #pragma unroll
        for (int ks = 0; ks < 2; ++ks) {
            f16x4 a0 = *(const f16x4*)&As[32 * wm + lrow][ks * 16 + g * 4];
            f16x4 a1 = *(const f16x4*)&As[32 * wm + 16 + lrow][ks * 16 + g * 4];
            f16x4 b0 = *(const f16x4*)&Bs[32 * wn + lrow][ks * 16 + g * 4];
            f16x4 b1 = *(const f16x4*)&Bs[32 * wn + 16 + lrow][ks * 16 + g * 4];
            acc[0][0] = __builtin_amdgcn_mfma_f32_16x16x16f16(a0, b0, acc[0][0], 0, 0, 0);
            acc[0][1] = __builtin_amdgcn_mfma_f32_16x16x16f16(a0, b1, acc[0][1], 0, 0, 0);
            acc[1][0] = __builtin_amdgcn_mfma_f32_16x16x16f16(a1, b0, acc[1][0], 0, 0, 0);
            acc[1][1] = __builtin_amdgcn_mfma_f32_16x16x16f16(a1, b1, acc[1][1], 0, 0, 0);
        }
        __syncthreads();
    }

    #pragma unroll
    for (int mt = 0; mt < 2; ++mt)
        #pragma unroll
        for (int nt = 0; nt < 2; ++nt) {
            int n = block_n + 32 * wn + 16 * nt + lrow;
            float bv = bias ? bias[n] : 0.0f;
            #pragma unroll
            for (int i = 0; i < 4; ++i) {
                int m = block_m + 32 * wm + 16 * mt + g * 4 + i;
                C[(size_t)m * ldc + n] = acc[mt][nt][i] * alpha + bv;
            }
        }
}

// ---------------------------------------------------------------------------
// FUSED LML solve + PV. One 4-wave block per row; wave w solves nu for
// N = 2w+1, 2w+2.  Solver (round-9 proven): quartic-series init + 4
// bracket-guarded full Newton evals with INCLUSIVE-bound guard.
//
// PV (round-10 restructure): lane = (q, d4): q = lane>>4 picks j = q mod 4,
// d = (lane&15)*4..+3.  Per iteration: ONE float4 V load per lane (4 j-rows
// x 64 d = 1 KB/wave-inst, fully coalesced; was 4 x 256B dword loads) and
// 8 ds_read_b32 at 4 consecutive-bank broadcast addresses (was 8 broadcast
// b128).  acc[8][4] in registers; cross-q-group butterfly reduce
// (shfl_xor 16/32); lanes 0-15 write float4 ow rows.  fma count unchanged.
// ---------------------------------------------------------------------------
__global__ __launch_bounds__(256) void solve_pv_kernel(
    const float* __restrict__ dots, const float* __restrict__ qkv,
    float* __restrict__ y)
{
    int r = blockIdx.x;
    int b = r >> 10;
    int t = threadIdx.x;
    int wave = t >> 6, lane = t & 63;
    int nbase = wave * 2;            // this wave solves N = nbase+1, nbase+2

    __shared__ float p_lds[8][1024];  // 32 KB; first 8 KB reused as ow later

    const float* x = dots + (size_t)r * SEQ;

    float e[16];
    #pragma unroll
    for (int s = 0; s < 4; ++s) {
        float4 v = *(const float4*)(x + lane * 4 + 256 * s);
        e[4 * s + 0] = v.x; e[4 * s + 1] = v.y;
        e[4 * s + 2] = v.z; e[4 * s + 3] = v.w;
    }
    float mx = e[0], mn = e[0];
    #pragma unroll
    for (int s = 1; s < 16; ++s) { mx = fmaxf(mx, e[s]); mn = fminf(mn, e[s]); }
    #pragma unroll
    for (int off = 32; off; off >>= 1) {
        mx = fmaxf(mx, __shfl_xor(mx, off));
        mn = fminf(mn, __shfl_xor(mn, off));
    }
    #pragma unroll
    for (int s = 0; s < 16; ++s) e[s] = __expf(e[s]);

    // E1..E4 = sums of e^x, e^2x, e^3x, e^4x (for the series init)
    float E1 = 0, E2 = 0, E3 = 0, E4 = 0;
    #pragma unroll
    for (int s = 0; s < 16; ++s) {
        float u = e[s], u2 = u * u;
        E1 += u; E2 += u2; E3 += u2 * u; E4 += u2 * u2;
    }
    #pragma unroll
    for (int off = 32; off; off >>= 1) {
        E1 += __shfl_xor(E1, off); E2 += __shfl_xor(E2, off);
        E3 += __shfl_xor(E3, off); E4 += __shfl_xor(E4, off);
    }

    float lo[2], hi[2], Nf[2], nu[2];
    #pragma unroll
    for (int k = 0; k < 2; ++k) {
        int N = nbase + k + 1;
        Nf[k] = (float)N;
        float lgt = __logf((float)N / (float)(SEQ - N));
        lo[k] = lgt - mx;             // provable bracket
        hi[k] = lgt - mn;
        // scalar Newton on the quartic series in t = e^nu
        float t0 = Nf[k] * __builtin_amdgcn_rcpf(E1);
        float tt = t0;
        #pragma unroll
        for (int it = 0; it < 4; ++it) {
            float gg = tt * (E1 + tt * (-E2 + tt * (E3 - tt * E4))) - Nf[k];
            float gp = E1 + tt * (-2.0f * E2 + tt * (3.0f * E3 - 4.0f * E4 * tt));
            float tn = tt - gg * __builtin_amdgcn_rcpf(gp);
            tt = (tn > 0.0f && tn < 1.0f) ? tn : t0;
        }
        float v = __logf(tt);
        nu[k] = (v > lo[k] && v < hi[k]) ? v : 0.5f * (lo[k] + hi[k]);
    }

    // ---- 4 bracket-guarded full Newton evals (inclusive-bound guard) ----
    for (int it = 0; it < 4; ++it) {
        float S[2], Sp[2];
        #pragma unroll
        for (int k = 0; k < 2; ++k) {
            float tn = __expf(nu[k]);
            float sn = 0.0f, spn = 0.0f;
            #pragma unroll
            for (int s = 0; s < 8; ++s) {
                float u1 = e[2 * s] * tn, u2 = e[2 * s + 1] * tn;
                float a1 = 1.0f + u1, a2 = 1.0f + u2;
                float rr = __builtin_amdgcn_rcpf(a1 * a2);
                float inv1 = rr * a2, inv2 = rr * a1;     // = 1/a1, 1/a2
                float p1 = u1 * inv1, p2 = u2 * inv2;
                sn += p1 + p2;
                spn = fmaf(p1, inv1, spn);                // p(1-p) = p*inv
                spn = fmaf(p2, inv2, spn);
            }
            S[k] = sn; Sp[k] = spn;
        }
        #pragma unroll
        for (int k = 0; k < 2; ++k) {
            #pragma unroll
            for (int off = 32; off; off >>= 1) {
                S[k]  += __shfl_xor(S[k], off);
                Sp[k] += __shfl_xor(Sp[k], off);
            }
            if (S[k] < Nf[k]) lo[k] = nu[k]; else hi[k] = nu[k];
            float step = (Nf[k] - S[k]) * __builtin_amdgcn_rcpf(Sp[k]);
            float cand = nu[k] + step;
            if (!(cand >= lo[k] && cand <= hi[k])) cand = 0.5f * (lo[k] + hi[k]);
            nu[k] = cand;
        }
    }

    // ---- write p for this wave's 2 nus from register e[] ----
    #pragma unroll
    for (int k = 0; k < 2; ++k) {
        float tn = __expf(nu[k]);
        #pragma unroll
        for (int s = 0; s < 4; ++s) {
            float u0 = e[4 * s + 0] * tn, u1 = e[4 * s + 1] * tn;
            float u2 = e[4 * s + 2] * tn, u3 = e[4 * s + 3] * tn;
            float4 pp;
            pp.x = u0 * __builtin_amdgcn_rcpf(1.0f + u0);
            pp.y = u1 * __builtin_amdgcn_rcpf(1.0f + u1);
            pp.z = u2 * __builtin_amdgcn_rcpf(1.0f + u2);
            pp.w = u3 * __builtin_amdgcn_rcpf(1.0f + u3);
            *(float4*)&p_lds[nbase + k][lane * 4 + 256 * s] = pp;
        }
    }
    __syncthreads();

    // ---- PV: wave w covers j in [256w, 256w+256); lane = (q, d4) ----
    int q = lane >> 4;          // j = jbase + 4*jj + q
    int dgrp = lane & 15;       // d = dgrp*4 .. dgrp*4+3
    int jbase = wave * 256;
    const float* vrow = qkv + ((size_t)b * SEQ + jbase + q) * QKV3
                      + 2 * DIM_HEAD + dgrp * 4;
    float acc[8][4] = {};
    #pragma unroll 4
    for (int jj = 0; jj < 64; ++jj) {
        float4 v = *(const float4*)(vrow + (size_t)jj * 4 * QKV3);
        int jw = jbase + 4 * jj + q;
        float pv[8];
        #pragma unroll
        for (int n = 0; n < 8; ++n) pv[n] = p_lds[n][jw];
        #pragma unroll
        for (int n = 0; n < 8; ++n) {
            acc[n][0] = fmaf(pv[n], v.x, acc[n][0]);
            acc[n][1] = fmaf(pv[n], v.y, acc[n][1]);
            acc[n][2] = fmaf(pv[n], v.z, acc[n][2]);
            acc[n][3] = fmaf(pv[n], v.w, acc[n][3]);
        }
    }

    // reduce across the 4 q-groups (lanes xor 16, 32)
    #pragma unroll
    for (int n = 0; n < 8; ++n)
        #pragma unroll
        for (int d = 0; d < 4; ++d) {
            acc[n][d] += __shfl_xor(acc[n][d], 16);
            acc[n][d] += __shfl_xor(acc[n][d], 32);
        }

    __syncthreads();   // all p reads done; safe to overlay ow on p_lds
    float (*ow)[8][64] = (float (*)[8][64])&p_lds[0][0];   // 8 KB overlay
    if (lane < 16) {
        #pragma unroll
        for (int n = 0; n < 8; ++n) {
            float4 o4 = { acc[n][0], acc[n][1], acc[n][2], acc[n][3] };
            *(float4*)&ow[wave][n][dgrp * 4] = o4;
        }
    }
    __syncthreads();

    // reduce across waves + head differences -> y[r][h*64+d]
    float* yr = y + (size_t)r * (HEADS * DIM_HEAD);
    #pragma unroll
    for (int s = 0; s < 2; ++s) {
        int c = t + 256 * s;
        int h = c >> 6, dd = c & 63;
        float oh = ow[0][h][dd] + ow[1][h][dd] + ow[2][h][dd] + ow[3][h][dd];
        float op = 0.0f;
        if (h) op = ow[0][h - 1][dd] + ow[1][h - 1][dd] + ow[2][h - 1][dd] + ow[3][h - 1][dd];
        yr[c] = oh - op;
    }
}

// ---------------------------------------------------------------------------
extern "C" void kernel_launch(void* const* d_in, const int* in_sizes, int n_in,
                              void* d_out, int out_size, void* d_ws, size_t ws_size,
                              hipStream_t stream)
{
    const float* x       = (const float*)d_in[0];
    const float* ln_g    = (const float*)d_in[1];
    const float* ln_b    = (const float*)d_in[2];
    const float* w_qkv   = (const float*)d_in[3];
    const float* w_out   = (const float*)d_in[4];
    const float* b_out   = (const float*)d_in[5];
    float* out = (float*)d_out;

    // ws: xn[ROWS*DIM] | qkv[ROWS*192] | dots[4M]   (~28.5 MB)
    float* xn   = (float*)d_ws;
    float* qkv  = xn + (size_t)ROWS * DIM;
    float* dots = qkv + (size_t)ROWS * QKV3;
    float* y    = xn;  // reuse (dead after qkv GEMM; rewritten by solve_pv)

    // 1) LayerNorm
    ln_kernel<<<ROWS, 256, 0, stream>>>(x, ln_g, ln_b, xn);

    // 2) qkv = xn @ w_qkv   [4096,512]x[512,192]
    gemm16_kernel<0><<<dim3(QKV3 / 64, ROWS / 64, 1), 256, 0, stream>>>(
        xn, w_qkv, qkv, nullptr,
        DIM, DIM, QKV3, QKV3, 0, 0, 0, 1.0f);

    // 3) dots[b] = 0.125 * q[b] @ k[b]^T   batched [1024,64]x[64,1024]
    gemm16_kernel<1><<<dim3(SEQ / 64, SEQ / 64, Bsz), 256, 0, stream>>>(
        qkv, qkv + DIM_HEAD, dots, nullptr,
        DIM_HEAD, QKV3, QKV3, SEQ,
        (long)SEQ * QKV3, (long)SEQ * QKV3, (long)SEQ * SEQ, 0.125f);

    // 4) fused LML solve + PV + head differences -> y [4096, 512]
    solve_pv_kernel<<<ROWS, 256, 0, stream>>>(dots, qkv, y);

    // 5) out = y @ w_out + b_out   [4096,512]x[512,512]
    gemm16_kernel<0><<<dim3(DIM / 64, ROWS / 64, 1), 256, 0, stream>>>(
        y, w_out, out, b_out,
        DIM, DIM, DIM, DIM, 0, 0, 0, 1.0f);
}